// Round 3
// baseline (317.519 us; speedup 1.0000x reference)
//
#include <hip/hip_runtime.h>
#include <math.h>

// out = relu( tile(pool2(x1),2) + tile(pool4(x2),4) + tile(pool8(x3),8)
//             + tile(pool16(x4),16) + ff )   all NCHW fp32, B=16, out 16x256x24x24.
//
// Round-6: force memory-level parallelism with inline-asm loads.
// Evidence: rounds 3/4/5 all issue exactly 285,696 wave-loads and all take
// 116+-2us regardless of occupancy (26/60/43%) or HBM bytes (169 vs 221 MB)
// -> latency-bound at ~3-4 outstanding wave-loads per CU. The compiler twice
// defeated source-level load batching (VGPR stayed 32/48: loads sunk into
// consume points). Fix: asm volatile global_load_dwordx4 issued back-to-back
// (cannot be reordered), consumed in issue order with counted s_waitcnt
// vmcnt(28/24/16/0) + sched_barrier(0) after each wait (rule #18: VALU
// consumers can otherwise hoist past an inline-asm waitcnt).
//
// __launch_bounds__(256,2): 256-VGPR budget so the ~140 live VGPRs (124 data)
// can NEVER spill -- a spilled un-landed asm dest would store garbage.
// 8 waves/CU x 31KB in flight = 248KB/CU >> the ~9KB needed for peak BW.

namespace {

typedef float f32x4 __attribute__((ext_vector_type(4)));

#define GLOAD4(dst, p) \
  asm volatile("global_load_dwordx4 %0, %1, off" : "=v"(dst) : "v"(p))

#define WAITV(n)                                              \
  asm volatile("s_waitcnt vmcnt(" #n ")" ::: "memory");       \
  __builtin_amdgcn_sched_barrier(0)

__device__ __forceinline__ float fmax4(const f32x4 v) {
  return fmaxf(fmaxf(v.x, v.y), fmaxf(v.z, v.w));
}

__device__ __forceinline__ f32x4 max4(const f32x4 a, const f32x4 b) {
  f32x4 r;
  r.x = fmaxf(a.x, b.x); r.y = fmaxf(a.y, b.y);
  r.z = fmaxf(a.z, b.z); r.w = fmaxf(a.w, b.w);
  return r;
}

__global__ __launch_bounds__(256, 2) void fused_block(const float* __restrict__ x1,
                                                      const float* __restrict__ x2,
                                                      const float* __restrict__ x3,
                                                      const float* __restrict__ x4,
                                                      const float* __restrict__ ff,
                                                      float* __restrict__ out) {
  // Transposed pooled tiles: s*t[col][ch], col = 0..3 of this block's 4 output cols.
  __shared__ float s1t[4 * 128];
  __shared__ float s2t[4 * 64];
  __shared__ float s3t[4 * 32];
  __shared__ float s4t[4 * 16];

  const int blk  = blockIdx.x;      // 0..2303
  const int b    = blk / 144;
  const int rem  = blk % 144;
  const int oh   = rem / 6;         // 0..23
  const int quad = rem % 6;         // output cols quad*4 .. quad*4+3
  const int tid  = threadIdx.x;

  // ============ ISSUE PHASE: 31 asm loads, back-to-back, in this order ============
  // #1: ff | #2-3: A | #4-7: B | #8-15: C | #16-31: D
  // vmcnt retires in order -> counted waits below.

  f32x4 f;
  const size_t o = (size_t)b * 147456 + (size_t)tid * 576 + (size_t)oh * 24 + quad * 4;
  GLOAD4(f, ff + o);

  // A: x1 [16,128,48,48], K=2. task = ch(128) x pid(2); 1 float4 = 2 windows.
  const int chA = tid >> 1, pidA = tid & 1;
  const float* pA = x1 + (size_t)b * 294912 + (size_t)chA * 2304
                       + oh * 96 + quad * 8 + pidA * 4;
  f32x4 a0, a1;
  GLOAD4(a0, pA);
  GLOAD4(a1, pA + 48);

  // B: x2 [16,64,96,96], K=4. task = ch(64) x ow(4).
  const int chB = tid >> 2, owB = tid & 3;
  const float* pB = x2 + (size_t)b * 589824 + (size_t)chB * 9216
                       + oh * 384 + quad * 16 + owB * 4;
  f32x4 bv[4];
  GLOAD4(bv[0], pB);
  GLOAD4(bv[1], pB + 96);
  GLOAD4(bv[2], pB + 192);
  GLOAD4(bv[3], pB + 288);

  // C: x3 [16,32,192,192], K=8. task = ch(32) x ow(4) x hf(2); 2 lanes/window.
  const int chC = tid >> 3, owC = (tid >> 1) & 3, hf = tid & 1;
  const float* pC = x3 + (size_t)b * 1179648 + (size_t)chC * 36864
                       + oh * 1536 + quad * 32 + owC * 8 + hf * 4;
  f32x4 cv[8];
  GLOAD4(cv[0], pC);
  GLOAD4(cv[1], pC + 192);
  GLOAD4(cv[2], pC + 384);
  GLOAD4(cv[3], pC + 576);
  GLOAD4(cv[4], pC + 768);
  GLOAD4(cv[5], pC + 960);
  GLOAD4(cv[6], pC + 1152);
  GLOAD4(cv[7], pC + 1344);

  // D: x4 [16,16,384,384], K=16. task = ch(16) x ow(4) x q(4); 4 lanes/window.
  const int chD = tid >> 4, owD = (tid >> 2) & 3, q = tid & 3;
  const float* pD = x4 + (size_t)b * 2359296 + (size_t)chD * 147456
                       + oh * 6144 + quad * 64 + owD * 16 + q * 4;
  f32x4 dv[16];
  GLOAD4(dv[0],  pD);
  GLOAD4(dv[1],  pD + 384);
  GLOAD4(dv[2],  pD + 768);
  GLOAD4(dv[3],  pD + 1152);
  GLOAD4(dv[4],  pD + 1536);
  GLOAD4(dv[5],  pD + 1920);
  GLOAD4(dv[6],  pD + 2304);
  GLOAD4(dv[7],  pD + 2688);
  GLOAD4(dv[8],  pD + 3072);
  GLOAD4(dv[9],  pD + 3456);
  GLOAD4(dv[10], pD + 3840);
  GLOAD4(dv[11], pD + 4224);
  GLOAD4(dv[12], pD + 4608);
  GLOAD4(dv[13], pD + 4992);
  GLOAD4(dv[14], pD + 5376);
  GLOAD4(dv[15], pD + 5760);

  // ============ CONSUME PHASE: issue order, counted vmcnt waits ============

  // A ready when 28 remain outstanding (loads #2,#3 of 31).
  WAITV(28);
  s1t[(pidA * 2) * 128 + chA]     = fmaxf(fmaxf(a0.x, a0.y), fmaxf(a1.x, a1.y));
  s1t[(pidA * 2 + 1) * 128 + chA] = fmaxf(fmaxf(a0.z, a0.w), fmaxf(a1.z, a1.w));

  // B ready at 24 remaining.
  WAITV(24);
  {
    const f32x4 u = max4(max4(bv[0], bv[1]), max4(bv[2], bv[3]));
    s2t[owB * 64 + chB] = fmax4(u);
  }

  // C ready at 16 remaining (D's 16 still in flight).
  WAITV(16);
  {
    const f32x4 u0 = max4(cv[0], cv[1]), u1 = max4(cv[2], cv[3]);
    const f32x4 u2 = max4(cv[4], cv[5]), u3 = max4(cv[6], cv[7]);
    float m = fmax4(max4(max4(u0, u1), max4(u2, u3)));
    m = fmaxf(m, __shfl_xor(m, 1));
    if (hf == 0) s3t[owC * 32 + chC] = m;
  }

  // D (and ff, the oldest) ready at 0 remaining.
  WAITV(0);
  {
    f32x4 t0 = max4(dv[0], dv[8]),  t1 = max4(dv[1], dv[9]);
    f32x4 t2 = max4(dv[2], dv[10]), t3 = max4(dv[3], dv[11]);
    f32x4 t4 = max4(dv[4], dv[12]), t5 = max4(dv[5], dv[13]);
    f32x4 t6 = max4(dv[6], dv[14]), t7 = max4(dv[7], dv[15]);
    const f32x4 u0 = max4(t0, t1), u1 = max4(t2, t3);
    const f32x4 u2 = max4(t4, t5), u3 = max4(t6, t7);
    float m = fmax4(max4(max4(u0, u1), max4(u2, u3)));
    m = fmaxf(m, __shfl_xor(m, 1));
    m = fmaxf(m, __shfl_xor(m, 2));
    if (q == 0) s4t[owD * 16 + chD] = m;
  }

  __syncthreads();

  // E: combine. task = channel(256); float4 over this block's 4 cols.
  {
    const int c1 = tid & 127, c2 = tid & 63, c3 = tid & 31, c4 = tid & 15;
    float4 r;
    r.x = fmaxf(s1t[0 * 128 + c1] + s2t[0 * 64 + c2] + s3t[0 * 32 + c3] + s4t[0 * 16 + c4] + f.x, 0.0f);
    r.y = fmaxf(s1t[1 * 128 + c1] + s2t[1 * 64 + c2] + s3t[1 * 32 + c3] + s4t[1 * 16 + c4] + f.y, 0.0f);
    r.z = fmaxf(s1t[2 * 128 + c1] + s2t[2 * 64 + c2] + s3t[2 * 32 + c3] + s4t[2 * 16 + c4] + f.z, 0.0f);
    r.w = fmaxf(s1t[3 * 128 + c1] + s2t[3 * 64 + c2] + s3t[3 * 32 + c3] + s4t[3 * 16 + c4] + f.w, 0.0f);
    *reinterpret_cast<float4*>(out + o) = r;
  }
}

}  // namespace

extern "C" void kernel_launch(void* const* d_in, const int* in_sizes, int n_in,
                              void* d_out, int out_size, void* d_ws, size_t ws_size,
                              hipStream_t stream) {
  const float* x1 = (const float*)d_in[0];  // [16,128,48,48]
  const float* x2 = (const float*)d_in[1];  // [16,64,96,96]
  const float* x3 = (const float*)d_in[2];  // [16,32,192,192]
  const float* x4 = (const float*)d_in[3];  // [16,16,384,384]
  const float* ff = (const float*)d_in[4];  // [16,256,24,24]
  float* out = (float*)d_out;               // [16,256,24,24]
  (void)d_ws; (void)ws_size; (void)in_sizes; (void)n_in; (void)out_size;

  fused_block<<<2304, 256, 0, stream>>>(x1, x2, x3, x4, ff, out);
}